// Round 13
// baseline (27.183 us; speedup 1.0000x reference)
//
#include <hip/hip_runtime.h>
#include <math.h>
#include <stdint.h>

constexpr int Hn = 512, Wn = 512, Bn = 16;
constexpr int GX = 2;               // 256-col tiles (4 px/lane)
constexpr int GY = 32;              // 16-row groups (4 waves x 4 rows)
constexpr int NBLK = GX * GY * Bn;  // 1024 blocks
#define NACC 11
constexpr float NTOT = 16.f * 512.f * 512.f;

typedef float f4 __attribute__((ext_vector_type(4)));

// partials (transposed [i][blk]): 0 bce, 1 sum_d, 2 sum_t, 3 sum_dt,
//   4..6 cnt(3,5,7), 7..9 bce*mask(3,5,7), 10 detail

__device__ __forceinline__ f4 ld4(const float* p) {
    f4 r;
    asm volatile("global_load_dwordx4 %0, %1, off" : "=v"(r) : "v"(p) : "memory");
    return r;
}
__device__ __forceinline__ float ld1(const float* p) {
    float r;
    asm volatile("global_load_dword %0, %1, off" : "=v"(r) : "v"(p) : "memory");
    return r;
}
__device__ __forceinline__ uint32_t bits4v(f4 v) {
    return (uint32_t)(v[0] > 0.5f) | ((uint32_t)(v[1] > 0.5f) << 1) |
           ((uint32_t)(v[2] > 0.5f) << 2) | ((uint32_t)(v[3] > 0.5f) << 3);
}
__device__ __forceinline__ float sigm(float x) {
    const float z = __expf(-fabsf(x));
    const float r = __builtin_amdgcn_rcpf(1.f + z);
    return (x >= 0.f) ? r : 1.f - r;
}
__device__ __forceinline__ void pxd(float x, float tf, float& d) {
    const float z = __expf(-fabsf(x));
    const float r = __builtin_amdgcn_rcpf(1.f + z);
    d = ((x >= 0.f) ? r : 1.f - r) - tf;
}
__device__ __forceinline__ void pxb(float x, float tf, float& d, float& b) {
    const float z = __expf(-fabsf(x));
    const float r = __builtin_amdgcn_rcpf(1.f + z);
    d = ((x >= 0.f) ? r : 1.f - r) - tf;
    b = fmaxf((1.f - 2.f * tf) * x, 0.f) + __logf(1.f + z);
}
__device__ __forceinline__ int iclamp(int v, int lo, int hi) {
    return v < lo ? lo : (v > hi ? hi : v);
}

__global__ __launch_bounds__(256, 2) void crack_main(
    const float* __restrict__ logits, const float* __restrict__ target,
    float* __restrict__ partials)
{
    const int tid  = threadIdx.x;
    const int lane = tid & 63;
    const int wid  = __builtin_amdgcn_readfirstlane(tid >> 6);

    // XCD-chunked swizzle: blocks on one XCD cover contiguous y (halo reuse in L2)
    const int lin = blockIdx.x + GX * (blockIdx.y + GY * blockIdx.z);
    const int vid = (lin & 7) * (NBLK / 8) + (lin >> 3);
    const int by  = vid % GY;
    const int bx  = (vid / GY) & (GX - 1);
    const int bz  = vid / (GY * GX);

    const int x0 = bx * 256;
    const int y0 = by * 16 + wid * 4;             // wave owns rows y0..y0+3
    const int cx = x0 + 4 * lane;                 // my 4 columns
    const size_t base = (size_t)bz * (size_t)(Hn * Wn);
    const bool leftE  = (x0 == 0);
    const bool rightE = (x0 + 256 >= Wn);

    uint32_t validm = 0xFFFu;                     // erosion-complement validity
    if (leftE  && lane == 0)  validm = 0xFF0u;
    if (rightE && lane == 63) validm = 0x0FFu;

    // ====== ALL loads via inline asm: forced batch issue, forced live regs ======
    f4 tf[10];
#pragma unroll
    for (int r = 0; r < 10; ++r) {
        const int gyc = iclamp(y0 - 3 + r, 0, Hn - 1);
        tf[r] = ld4(target + base + (size_t)gyc * Wn + cx);
    }
    f4 ef;
    {
        const int q = lane & 31, side = lane >> 5;
        const int gyc = iclamp(y0 - 3 + (q < 10 ? q : 9), 0, Hn - 1);
        const int exc = side ? iclamp(x0 + 256, 0, Wn - 4) : iclamp(x0 - 4, 0, Wn - 4);
        ef = ld4(target + base + (size_t)gyc * Wn + exc);
    }
    f4 xf[6];
#pragma unroll
    for (int rr = 0; rr < 6; ++rr) {
        const int gyc = iclamp(y0 - 1 + rr, 0, Hn - 1);
        xf[rr] = ld4(logits + base + (size_t)gyc * Wn + cx);
    }
    float edx, edt;
    {
        const int q = lane & 31, side = lane >> 5;
        const int gyc = y0 + (q < 4 ? q : 3);
        const int exc = side ? iclamp(x0 + 256, 0, Wn - 1) : iclamp(x0 - 1, 0, Wn - 1);
        edx = ld1(logits + base + (size_t)gyc * Wn + exc);
        edt = ld1(target + base + (size_t)gyc * Wn + exc);
    }
    asm volatile("s_waitcnt vmcnt(0)" ::: "memory");
    __builtin_amdgcn_sched_barrier(0);            // consumers may not hoist above

    // ============ convert + mask (no loads below this line) ============
    uint32_t mb[10];
#pragma unroll
    for (int r = 0; r < 10; ++r) {
        const bool rowv = ((unsigned)(y0 - 3 + r) < (unsigned)Hn);
        mb[r] = rowv ? bits4v(tf[r]) : 0u;
    }
    uint32_t eb;
    {
        const int q = lane & 31, side = lane >> 5;
        const bool ev = (q < 10) && ((unsigned)(y0 - 3 + q) < (unsigned)Hn) &&
                        (side ? !rightE : !leftE);
        eb = ev ? bits4v(ef) : 0u;
    }
    float ed;
    {
        const int q = lane & 31, side = lane >> 5;
        const bool ev = (q < 4) && (side ? !rightE : !leftE);
        ed = ev ? (sigm(edx) - ((edt > 0.5f) ? 1.f : 0.f)) : 0.f;
    }

    // ---- morphology: shuffle neighbors, 12-bit window, dilate/erode cascades ----
    uint32_t po[10], pu[10];
#pragma unroll
    for (int r = 0; r < 10; ++r) {
        const uint32_t m = mb[r];
        uint32_t ml = __shfl_up(m, 1);
        uint32_t mr = __shfl_down(m, 1);
        const uint32_t el = __shfl(eb, r);
        const uint32_t er = __shfl(eb, 32 + r);
        if (lane == 0)  ml = el;
        if (lane == 63) mr = er;
        const uint32_t w = ml | (m << 4) | (mr << 8);    // bit b = col cx-4+b
        const bool rowv = ((unsigned)(y0 - 3 + r) < (unsigned)Hn);
        const uint32_t wc = rowv ? ((~w) & validm) : 0u;
        const uint32_t w1 = w  | (w  << 1) | (w  >> 1);
        const uint32_t w2 = w1 | (w1 << 1) | (w1 >> 1);
        const uint32_t w3 = w2 | (w2 << 1) | (w2 >> 1);
        const uint32_t u1 = wc | (wc << 1) | (wc >> 1);
        const uint32_t u2 = u1 | (u1 << 1) | (u1 >> 1);
        const uint32_t u3 = u2 | (u2 << 1) | (u2 >> 1);
        po[r] = ((w1 >> 4) & 0xFu) | (((w2 >> 4) & 0xFu) << 4) |
                (((w3 >> 4) & 0xFu) << 8);
        pu[r] = ((u1 >> 4) & 0xFu) | (((u2 >> 4) & 0xFu) << 4) |
                (((u3 >> 4) & 0xFu) << 8);
    }

    // ---- d field + bce + elementwise sums ----
    float4 da[6], b4c[4];
    float sbce = 0.f, sd = 0.f, sdt = 0.f, stt = 0.f;
#pragma unroll
    for (int rr = 0; rr < 6; ++rr) {
        const uint32_t m = mb[rr + 2];
        const float t0 = (float)(m & 1u), t1 = (float)((m >> 1) & 1u);
        const float t2 = (float)((m >> 2) & 1u), t3 = (float)((m >> 3) & 1u);
        const f4 x = xf[rr];
        if (rr >= 1 && rr <= 4) {                 // core rows (always valid)
            float4 d, bc;
            pxb(x[0], t0, d.x, bc.x); pxb(x[1], t1, d.y, bc.y);
            pxb(x[2], t2, d.z, bc.z); pxb(x[3], t3, d.w, bc.w);
            da[rr] = d; b4c[rr - 1] = bc;
            sbce += bc.x + bc.y + bc.z + bc.w;
            sd   += d.x + d.y + d.z + d.w;
            sdt  += d.x * t0 + d.y * t1 + d.z * t2 + d.w * t3;
            stt  += t0 + t1 + t2 + t3;
        } else {                                  // halo rows: d only, 0 if OOB
            const bool rowv = ((unsigned)(y0 - 1 + rr) < (unsigned)Hn);
            float4 d;
            pxd(x[0], t0, d.x); pxd(x[1], t1, d.y);
            pxd(x[2], t2, d.z); pxd(x[3], t3, d.w);
            if (!rowv) d = make_float4(0.f, 0.f, 0.f, 0.f);
            da[rr] = d;
        }
    }

    // ---- boundary combine + Laplacian on the 4 core rows ----
    float sb1 = 0.f, sb2 = 0.f, sb3 = 0.f, sdet = 0.f;
    int c1 = 0, c2 = 0, c3 = 0;
#pragma unroll
    for (int k = 0; k < 4; ++k) {                 // core row rr = k+1
        const uint32_t o3 = po[k + 2] | po[k + 3] | po[k + 4];
        const uint32_t o5 = o3 | po[k + 1] | po[k + 5];
        const uint32_t o7 = o5 | po[k] | po[k + 6];
        const uint32_t p3 = pu[k + 2] | pu[k + 3] | pu[k + 4];
        const uint32_t p5 = p3 | pu[k + 1] | pu[k + 5];
        const uint32_t p7 = p5 | pu[k] | pu[k + 6];
        const uint32_t vo = (o3 & 0xFu) | (o5 & 0xF0u) | (o7 & 0xF00u);
        const uint32_t vu = (p3 & 0xFu) | (p5 & 0xF0u) | (p7 & 0xF00u);
        const uint32_t b = vo & vu;               // [0:4) r1, [4:8) r2, [8:12) r3
        c1 += __popc(b & 0xFu);
        c2 += __popc(b & 0xF0u);
        c3 += __popc(b & 0xF00u);
        const float4 bc = b4c[k];
        sb1 += (((b >> 0) & 1) ? bc.x : 0.f) + (((b >> 1) & 1) ? bc.y : 0.f) +
               (((b >> 2) & 1) ? bc.z : 0.f) + (((b >> 3) & 1) ? bc.w : 0.f);
        sb2 += (((b >> 4) & 1) ? bc.x : 0.f) + (((b >> 5) & 1) ? bc.y : 0.f) +
               (((b >> 6) & 1) ? bc.z : 0.f) + (((b >> 7) & 1) ? bc.w : 0.f);
        sb3 += (((b >> 8) & 1) ? bc.x : 0.f) + (((b >> 9) & 1) ? bc.y : 0.f) +
               (((b >> 10) & 1) ? bc.z : 0.f) + (((b >> 11) & 1) ? bc.w : 0.f);

        const float4 ce = da[k + 1];
        const float4 up = da[k];
        const float4 dn = da[k + 2];
        float left = __shfl_up(ce.w, 1);
        { const float el = __shfl(ed, k); if (lane == 0)  left = el; }
        float right = __shfl_down(ce.x, 1);
        { const float er = __shfl(ed, 32 + k); if (lane == 63) right = er; }
        sdet += fabsf(left + ce.y + up.x + dn.x - 4.f * ce.x);
        sdet += fabsf(ce.x + ce.z + up.y + dn.y - 4.f * ce.y);
        sdet += fabsf(ce.y + ce.w + up.z + dn.z - 4.f * ce.z);
        sdet += fabsf(ce.z + right + up.w + dn.w - 4.f * ce.w);
    }

    // ---- block reduction -> partials (no atomics, no fences) ----
    float acc[NACC];
    acc[0] = sbce; acc[1] = sd; acc[2] = stt; acc[3] = sdt;
    acc[4] = (float)c1; acc[5] = (float)c2; acc[6] = (float)c3;
    acc[7] = sb1; acc[8] = sb2; acc[9] = sb3; acc[10] = sdet;
#pragma unroll
    for (int i = 0; i < NACC; ++i) {
        float v = acc[i];
#pragma unroll
        for (int off = 32; off; off >>= 1) v += __shfl_xor(v, off);
        acc[i] = v;
    }
    __shared__ float s_red[4][NACC];
    if (lane == 0) {
#pragma unroll
        for (int i = 0; i < NACC; ++i) s_red[wid][i] = acc[i];
    }
    __syncthreads();
    if (tid < NACC) {
        partials[(size_t)tid * NBLK + vid] =
            s_red[0][tid] + s_red[1][tid] + s_red[2][tid] + s_red[3][tid];
    }
}

__global__ __launch_bounds__(1024) void crack_final(
    const float* __restrict__ partials, float* __restrict__ out)
{
    const int tid = threadIdx.x;                  // 1024 threads == NBLK
    float a[NACC];
#pragma unroll
    for (int i = 0; i < NACC; ++i) a[i] = partials[(size_t)i * NBLK + tid];
    asm volatile("" ::: "memory");                // keep all 11 loads in flight
#pragma unroll
    for (int i = 0; i < NACC; ++i) {
        float v = a[i];
#pragma unroll
        for (int off = 32; off; off >>= 1) v += __shfl_xor(v, off);
        a[i] = v;
    }
    __shared__ float s_red[16][NACC];
    const int lane = tid & 63, wid = tid >> 6;
    if (lane == 0) {
#pragma unroll
        for (int i = 0; i < NACC; ++i) s_red[wid][i] = a[i];
    }
    __syncthreads();
    if (tid == 0) {
        float t[NACC];
        for (int i = 0; i < NACC; ++i) {
            float v = 0.f;
            for (int w = 0; w < 16; ++w) v += s_red[w][i];
            t[i] = v;
        }
        const float bce   = t[0] / NTOT;
        const float st    = t[2];
        const float sp    = t[1] + t[2];
        const float inter = t[3] + t[2];
        const float dice = 1.f - (2.f * inter + 1.f) / (sp + st + 1.f);
        const float fp = sp - inter, fn = st - inter;
        const float tvi = (inter + 1.f) / (inter + 0.6f * fp + 0.4f * fn + 1.f);
        const float tversky = powf(fmaxf(1.f - tvi, 0.f), 0.75f);
        float tb = 0.f, ns = 0.f;
        for (int i = 0; i < 3; ++i) {
            const float cnt = t[4 + i], sb = t[7 + i];
            if (cnt >= 1.f) { tb += sb / cnt; ns += 1.f; }
        }
        const float boundary = (ns > 0.f) ? tb / ns : 0.f;
        const float detail = t[10] / NTOT;
        out[0] = bce + dice + 0.5f * tversky + 0.5f * boundary + 0.3f * detail;
    }
}

extern "C" void kernel_launch(void* const* d_in, const int* in_sizes, int n_in,
                              void* d_out, int out_size, void* d_ws, size_t ws_size,
                              hipStream_t stream) {
    const float* logits = (const float*)d_in[0];
    const float* target = (const float*)d_in[1];
    float* partials = (float*)d_ws;   // NACC * NBLK floats = 45 KiB, fully overwritten

    dim3 grid(GX, GY, Bn);
    crack_main<<<grid, dim3(256), 0, stream>>>(logits, target, partials);
    crack_final<<<1, 1024, 0, stream>>>(partials, (float*)d_out);
}

// Round 14
// 21.075 us; speedup vs baseline: 1.2898x; 1.2898x over previous
//
#include <hip/hip_runtime.h>
#include <math.h>
#include <stdint.h>

constexpr int Hn = 512, Wn = 512, Bn = 16;
constexpr int GX = 2;               // 256-col tiles (4 px/lane)
constexpr int GY = 32;              // 16-row groups (4 waves x 4 rows)
constexpr int NBLK = GX * GY * Bn;  // 1024 blocks
#define NACC 11
constexpr float NTOT = 16.f * 512.f * 512.f;

// partials (transposed [i][blk]): 0 bce, 1 sum_d, 2 sum_t, 3 sum_dt,
//   4..6 cnt(3,5,7), 7..9 bce*mask(3,5,7), 10 detail

__device__ __forceinline__ uint32_t bits4(float4 v) {
    return (uint32_t)(v.x > 0.5f) | ((uint32_t)(v.y > 0.5f) << 1) |
           ((uint32_t)(v.z > 0.5f) << 2) | ((uint32_t)(v.w > 0.5f) << 3);
}
__device__ __forceinline__ float sigm(float x) {
    const float z = __expf(-fabsf(x));
    const float r = __builtin_amdgcn_rcpf(1.f + z);
    return (x >= 0.f) ? r : 1.f - r;
}
__device__ __forceinline__ void pxd(float x, float tf, float& d) {
    const float z = __expf(-fabsf(x));
    const float r = __builtin_amdgcn_rcpf(1.f + z);
    d = ((x >= 0.f) ? r : 1.f - r) - tf;
}
__device__ __forceinline__ void pxb(float x, float tf, float& d, float& b) {
    const float z = __expf(-fabsf(x));
    const float r = __builtin_amdgcn_rcpf(1.f + z);
    d = ((x >= 0.f) ? r : 1.f - r) - tf;
    b = fmaxf((1.f - 2.f * tf) * x, 0.f) + __logf(1.f + z);
}
__device__ __forceinline__ int iclamp(int v, int lo, int hi) {
    return v < lo ? lo : (v > hi ? hi : v);
}

__global__ __launch_bounds__(256) void crack_main(
    const float* __restrict__ logits, const float* __restrict__ target,
    float* __restrict__ partials)
{
    const int tid  = threadIdx.x;
    const int lane = tid & 63;
    const int wid  = __builtin_amdgcn_readfirstlane(tid >> 6);

    // XCD-chunked swizzle: blocks on one XCD cover contiguous y (halo reuse in L2)
    const int lin = blockIdx.x + GX * (blockIdx.y + GY * blockIdx.z);
    const int vid = (lin & 7) * (NBLK / 8) + (lin >> 3);
    const int by  = vid % GY;
    const int bx  = (vid / GY) & (GX - 1);
    const int bz  = vid / (GY * GX);

    const int x0 = bx * 256;
    const int y0 = by * 16 + wid * 4;             // wave owns rows y0..y0+3
    const int cx = x0 + 4 * lane;                 // my 4 columns
    const size_t base = (size_t)bz * (size_t)(Hn * Wn);
    const bool leftE  = (x0 == 0);
    const bool rightE = (x0 + 256 >= Wn);

    uint32_t validm = 0xFFFu;                     // erosion-complement validity
    if (leftE  && lane == 0)  validm = 0xFF0u;
    if (rightE && lane == 63) validm = 0x0FFu;

    // ============ ALL loads unconditional (clamped addresses), hoisted ============
    float4 tf[10];
#pragma unroll
    for (int r = 0; r < 10; ++r) {
        const int gyc = iclamp(y0 - 3 + r, 0, Hn - 1);
        tf[r] = *(const float4*)(target + base + (size_t)gyc * Wn + cx);
    }
    // strip-edge target word: lane q rows y0-3+q; side 0 cols x0-4.., side 1 x0+256..
    float4 ef;
    {
        const int q = lane & 31, side = lane >> 5;
        const int gyc = iclamp(y0 - 3 + (q < 10 ? q : 9), 0, Hn - 1);
        const int exc = side ? iclamp(x0 + 256, 0, Wn - 4) : iclamp(x0 - 4, 0, Wn - 4);
        ef = *(const float4*)(target + base + (size_t)gyc * Wn + exc);
    }
    float4 xf[6];
#pragma unroll
    for (int rr = 0; rr < 6; ++rr) {
        const int gyc = iclamp(y0 - 1 + rr, 0, Hn - 1);
        xf[rr] = *(const float4*)(logits + base + (size_t)gyc * Wn + cx);
    }
    // Laplacian edge columns: lane q rows y0+q (q<4); side 0 col x0-1, side 1 x0+256
    float edx, edt;
    {
        const int q = lane & 31, side = lane >> 5;
        const int gyc = y0 + (q < 4 ? q : 3);
        const int exc = side ? iclamp(x0 + 256, 0, Wn - 1) : iclamp(x0 - 1, 0, Wn - 1);
        edx = logits[base + (size_t)gyc * Wn + exc];
        edt = target[base + (size_t)gyc * Wn + exc];
    }

    // ============ convert + mask (no loads below this line) ============
    uint32_t mb[10];
#pragma unroll
    for (int r = 0; r < 10; ++r) {
        const bool rowv = ((unsigned)(y0 - 3 + r) < (unsigned)Hn);
        mb[r] = rowv ? bits4(tf[r]) : 0u;
    }
    uint32_t eb;
    {
        const int q = lane & 31, side = lane >> 5;
        const bool ev = (q < 10) && ((unsigned)(y0 - 3 + q) < (unsigned)Hn) &&
                        (side ? !rightE : !leftE);
        eb = ev ? bits4(ef) : 0u;
    }
    float ed;
    {
        const int q = lane & 31, side = lane >> 5;
        const bool ev = (q < 4) && (side ? !rightE : !leftE);
        ed = ev ? (sigm(edx) - ((edt > 0.5f) ? 1.f : 0.f)) : 0.f;
    }

    // ---- morphology: shuffle neighbors, 12-bit window, dilate/erode cascades ----
    uint32_t po[10], pu[10];
#pragma unroll
    for (int r = 0; r < 10; ++r) {
        const uint32_t m = mb[r];
        uint32_t ml = __shfl_up(m, 1);
        uint32_t mr = __shfl_down(m, 1);
        const uint32_t el = __shfl(eb, r);
        const uint32_t er = __shfl(eb, 32 + r);
        if (lane == 0)  ml = el;
        if (lane == 63) mr = er;
        const uint32_t w = ml | (m << 4) | (mr << 8);    // bit b = col cx-4+b
        const bool rowv = ((unsigned)(y0 - 3 + r) < (unsigned)Hn);
        const uint32_t wc = rowv ? ((~w) & validm) : 0u;
        const uint32_t w1 = w  | (w  << 1) | (w  >> 1);
        const uint32_t w2 = w1 | (w1 << 1) | (w1 >> 1);
        const uint32_t w3 = w2 | (w2 << 1) | (w2 >> 1);
        const uint32_t u1 = wc | (wc << 1) | (wc >> 1);
        const uint32_t u2 = u1 | (u1 << 1) | (u1 >> 1);
        const uint32_t u3 = u2 | (u2 << 1) | (u2 >> 1);
        po[r] = ((w1 >> 4) & 0xFu) | (((w2 >> 4) & 0xFu) << 4) |
                (((w3 >> 4) & 0xFu) << 8);
        pu[r] = ((u1 >> 4) & 0xFu) | (((u2 >> 4) & 0xFu) << 4) |
                (((u3 >> 4) & 0xFu) << 8);
    }

    // ---- d field + bce + elementwise sums ----
    float4 da[6], b4c[4];
    float sbce = 0.f, sd = 0.f, sdt = 0.f, stt = 0.f;
#pragma unroll
    for (int rr = 0; rr < 6; ++rr) {
        const uint32_t m = mb[rr + 2];
        const float t0 = (float)(m & 1u), t1 = (float)((m >> 1) & 1u);
        const float t2 = (float)((m >> 2) & 1u), t3 = (float)((m >> 3) & 1u);
        const float4 x = xf[rr];
        if (rr >= 1 && rr <= 4) {                 // core rows (always valid)
            float4 d, bc;
            pxb(x.x, t0, d.x, bc.x); pxb(x.y, t1, d.y, bc.y);
            pxb(x.z, t2, d.z, bc.z); pxb(x.w, t3, d.w, bc.w);
            da[rr] = d; b4c[rr - 1] = bc;
            sbce += bc.x + bc.y + bc.z + bc.w;
            sd   += d.x + d.y + d.z + d.w;
            sdt  += d.x * t0 + d.y * t1 + d.z * t2 + d.w * t3;
            stt  += t0 + t1 + t2 + t3;
        } else {                                  // halo rows: d only, 0 if OOB
            const bool rowv = ((unsigned)(y0 - 1 + rr) < (unsigned)Hn);
            float4 d;
            pxd(x.x, t0, d.x); pxd(x.y, t1, d.y);
            pxd(x.z, t2, d.z); pxd(x.w, t3, d.w);
            if (!rowv) d = make_float4(0.f, 0.f, 0.f, 0.f);
            da[rr] = d;
        }
    }

    // ---- boundary combine + Laplacian on the 4 core rows ----
    float sb1 = 0.f, sb2 = 0.f, sb3 = 0.f, sdet = 0.f;
    int c1 = 0, c2 = 0, c3 = 0;
#pragma unroll
    for (int k = 0; k < 4; ++k) {                 // core row rr = k+1
        const uint32_t o3 = po[k + 2] | po[k + 3] | po[k + 4];
        const uint32_t o5 = o3 | po[k + 1] | po[k + 5];
        const uint32_t o7 = o5 | po[k] | po[k + 6];
        const uint32_t p3 = pu[k + 2] | pu[k + 3] | pu[k + 4];
        const uint32_t p5 = p3 | pu[k + 1] | pu[k + 5];
        const uint32_t p7 = p5 | pu[k] | pu[k + 6];
        const uint32_t vo = (o3 & 0xFu) | (o5 & 0xF0u) | (o7 & 0xF00u);
        const uint32_t vu = (p3 & 0xFu) | (p5 & 0xF0u) | (p7 & 0xF00u);
        const uint32_t b = vo & vu;               // [0:4) r1, [4:8) r2, [8:12) r3
        c1 += __popc(b & 0xFu);
        c2 += __popc(b & 0xF0u);
        c3 += __popc(b & 0xF00u);
        const float4 bc = b4c[k];
        sb1 += (((b >> 0) & 1) ? bc.x : 0.f) + (((b >> 1) & 1) ? bc.y : 0.f) +
               (((b >> 2) & 1) ? bc.z : 0.f) + (((b >> 3) & 1) ? bc.w : 0.f);
        sb2 += (((b >> 4) & 1) ? bc.x : 0.f) + (((b >> 5) & 1) ? bc.y : 0.f) +
               (((b >> 6) & 1) ? bc.z : 0.f) + (((b >> 7) & 1) ? bc.w : 0.f);
        sb3 += (((b >> 8) & 1) ? bc.x : 0.f) + (((b >> 9) & 1) ? bc.y : 0.f) +
               (((b >> 10) & 1) ? bc.z : 0.f) + (((b >> 11) & 1) ? bc.w : 0.f);

        const float4 ce = da[k + 1];
        const float4 up = da[k];
        const float4 dn = da[k + 2];
        float left = __shfl_up(ce.w, 1);
        { const float el = __shfl(ed, k); if (lane == 0)  left = el; }
        float right = __shfl_down(ce.x, 1);
        { const float er = __shfl(ed, 32 + k); if (lane == 63) right = er; }
        sdet += fabsf(left + ce.y + up.x + dn.x - 4.f * ce.x);
        sdet += fabsf(ce.x + ce.z + up.y + dn.y - 4.f * ce.y);
        sdet += fabsf(ce.y + ce.w + up.z + dn.z - 4.f * ce.z);
        sdet += fabsf(ce.z + right + up.w + dn.w - 4.f * ce.w);
    }

    // ---- block reduction: 3 shuffle levels (8-lane groups) + LDS finish ----
    float acc[NACC];
    acc[0] = sbce; acc[1] = sd; acc[2] = stt; acc[3] = sdt;
    acc[4] = (float)c1; acc[5] = (float)c2; acc[6] = (float)c3;
    acc[7] = sb1; acc[8] = sb2; acc[9] = sb3; acc[10] = sdet;
#pragma unroll
    for (int i = 0; i < NACC; ++i) {
        float v = acc[i];
        v += __shfl_xor(v, 1);
        v += __shfl_xor(v, 2);
        v += __shfl_xor(v, 4);
        acc[i] = v;                               // lanes 0,8,..,56: 8-lane sums
    }
    __shared__ float s_red[32][NACC];             // 4 waves x 8 groups
    if ((lane & 7) == 0) {
#pragma unroll
        for (int i = 0; i < NACC; ++i) s_red[wid * 8 + (lane >> 3)][i] = acc[i];
    }
    __syncthreads();
    if (tid < NACC) {
        float v = 0.f;
#pragma unroll
        for (int g = 0; g < 32; ++g) v += s_red[g][tid];
        partials[(size_t)tid * NBLK + vid] = v;
    }
}

__global__ __launch_bounds__(704) void crack_final(
    const float* __restrict__ partials, float* __restrict__ out)
{
    const int tid = threadIdx.x;                  // 11 waves, one per slot
    const int lane = tid & 63;
    const int w = tid >> 6;                       // 0..10
    __shared__ float s_sum[NACC];

    float v = 0.f;
#pragma unroll
    for (int j = 0; j < NBLK / 64; ++j)           // 16 coalesced loads
        v += partials[(size_t)w * NBLK + j * 64 + lane];
#pragma unroll
    for (int off = 32; off; off >>= 1) v += __shfl_xor(v, off);
    if (lane == 0) s_sum[w] = v;
    __syncthreads();

    if (tid == 0) {
        float t[NACC];
#pragma unroll
        for (int i = 0; i < NACC; ++i) t[i] = s_sum[i];
        const float bce   = t[0] / NTOT;
        const float st    = t[2];
        const float sp    = t[1] + t[2];
        const float inter = t[3] + t[2];
        const float dice = 1.f - (2.f * inter + 1.f) / (sp + st + 1.f);
        const float fp = sp - inter, fn = st - inter;
        const float tvi = (inter + 1.f) / (inter + 0.6f * fp + 0.4f * fn + 1.f);
        const float tversky = powf(fmaxf(1.f - tvi, 0.f), 0.75f);
        float tb = 0.f, ns = 0.f;
        for (int i = 0; i < 3; ++i) {
            const float cnt = t[4 + i], sb = t[7 + i];
            if (cnt >= 1.f) { tb += sb / cnt; ns += 1.f; }
        }
        const float boundary = (ns > 0.f) ? tb / ns : 0.f;
        const float detail = t[10] / NTOT;
        out[0] = bce + dice + 0.5f * tversky + 0.5f * boundary + 0.3f * detail;
    }
}

extern "C" void kernel_launch(void* const* d_in, const int* in_sizes, int n_in,
                              void* d_out, int out_size, void* d_ws, size_t ws_size,
                              hipStream_t stream) {
    const float* logits = (const float*)d_in[0];
    const float* target = (const float*)d_in[1];
    float* partials = (float*)d_ws;   // NACC * NBLK floats = 45 KiB, fully overwritten

    dim3 grid(GX, GY, Bn);
    crack_main<<<grid, dim3(256), 0, stream>>>(logits, target, partials);
    crack_final<<<1, 704, 0, stream>>>(partials, (float*)d_out);
}

// Round 15
// 21.074 us; speedup vs baseline: 1.2899x; 1.0000x over previous
//
#include <hip/hip_runtime.h>
#include <math.h>
#include <stdint.h>

constexpr int Hn = 512, Wn = 512, Bn = 16;
constexpr int GX = 2;               // 256-col tiles (4 px/lane)
constexpr int GY = 32;              // 16-row groups (4 waves x 4 rows)
constexpr int NBLK = GX * GY * Bn;  // 1024 blocks
#define NACC 11
constexpr float NTOT = 16.f * 512.f * 512.f;

// partials (transposed [i][blk]): 0 bce, 1 sum_d, 2 sum_t, 3 sum_dt,
//   4..6 cnt(3,5,7), 7..9 bce*mask(3,5,7), 10 detail

__device__ __forceinline__ uint32_t bits4(float4 v) {
    return (uint32_t)(v.x > 0.5f) | ((uint32_t)(v.y > 0.5f) << 1) |
           ((uint32_t)(v.z > 0.5f) << 2) | ((uint32_t)(v.w > 0.5f) << 3);
}
__device__ __forceinline__ float sigm(float x) {
    const float z = __expf(-fabsf(x));
    const float r = __builtin_amdgcn_rcpf(1.f + z);
    return (x >= 0.f) ? r : 1.f - r;
}
__device__ __forceinline__ void pxd(float x, float tf, float& d) {
    const float z = __expf(-fabsf(x));
    const float r = __builtin_amdgcn_rcpf(1.f + z);
    d = ((x >= 0.f) ? r : 1.f - r) - tf;
}
__device__ __forceinline__ void pxb(float x, float tf, float& d, float& b) {
    const float z = __expf(-fabsf(x));
    const float r = __builtin_amdgcn_rcpf(1.f + z);
    d = ((x >= 0.f) ? r : 1.f - r) - tf;
    b = fmaxf((1.f - 2.f * tf) * x, 0.f) + __logf(1.f + z);
}
__device__ __forceinline__ int iclamp(int v, int lo, int hi) {
    return v < lo ? lo : (v > hi ? hi : v);
}

__global__ __launch_bounds__(256) void crack_main(
    const float* __restrict__ logits, const float* __restrict__ target,
    float* __restrict__ partials)
{
    const int tid  = threadIdx.x;
    const int lane = tid & 63;
    const int wid  = __builtin_amdgcn_readfirstlane(tid >> 6);

    // XCD-chunked swizzle: blocks on one XCD cover contiguous y (halo reuse in L2)
    const int lin = blockIdx.x + GX * (blockIdx.y + GY * blockIdx.z);
    const int vid = (lin & 7) * (NBLK / 8) + (lin >> 3);
    const int by  = vid % GY;
    const int bx  = (vid / GY) & (GX - 1);
    const int bz  = vid / (GY * GX);

    const int x0 = bx * 256;
    const int y0 = by * 16 + wid * 4;             // wave owns rows y0..y0+3
    const int cx = x0 + 4 * lane;                 // my 4 columns
    const size_t base = (size_t)bz * (size_t)(Hn * Wn);
    const bool leftE  = (x0 == 0);
    const bool rightE = (x0 + 256 >= Wn);

    uint32_t validm = 0xFFFu;                     // erosion-complement validity
    if (leftE  && lane == 0)  validm = 0xFF0u;
    if (rightE && lane == 63) validm = 0x0FFu;

    // ============ ALL loads unconditional (clamped addresses), hoisted ============
    float4 tf[10];
#pragma unroll
    for (int r = 0; r < 10; ++r) {
        const int gyc = iclamp(y0 - 3 + r, 0, Hn - 1);
        tf[r] = *(const float4*)(target + base + (size_t)gyc * Wn + cx);
    }
    // strip-edge target word: lane q rows y0-3+q; side 0 cols x0-4.., side 1 x0+256..
    float4 ef;
    {
        const int q = lane & 31, side = lane >> 5;
        const int gyc = iclamp(y0 - 3 + (q < 10 ? q : 9), 0, Hn - 1);
        const int exc = side ? iclamp(x0 + 256, 0, Wn - 4) : iclamp(x0 - 4, 0, Wn - 4);
        ef = *(const float4*)(target + base + (size_t)gyc * Wn + exc);
    }
    float4 xf[6];
#pragma unroll
    for (int rr = 0; rr < 6; ++rr) {
        const int gyc = iclamp(y0 - 1 + rr, 0, Hn - 1);
        xf[rr] = *(const float4*)(logits + base + (size_t)gyc * Wn + cx);
    }
    // Laplacian edge columns: lane q rows y0+q (q<4); side 0 col x0-1, side 1 x0+256
    float edx, edt;
    {
        const int q = lane & 31, side = lane >> 5;
        const int gyc = y0 + (q < 4 ? q : 3);
        const int exc = side ? iclamp(x0 + 256, 0, Wn - 1) : iclamp(x0 - 1, 0, Wn - 1);
        edx = logits[base + (size_t)gyc * Wn + exc];
        edt = target[base + (size_t)gyc * Wn + exc];
    }

    // ============ convert + mask ============
    uint32_t mb[10];
#pragma unroll
    for (int r = 0; r < 10; ++r) {
        const bool rowv = ((unsigned)(y0 - 3 + r) < (unsigned)Hn);
        mb[r] = rowv ? bits4(tf[r]) : 0u;
    }
    uint32_t eb;
    {
        const int q = lane & 31, side = lane >> 5;
        const bool ev = (q < 10) && ((unsigned)(y0 - 3 + q) < (unsigned)Hn) &&
                        (side ? !rightE : !leftE);
        eb = ev ? bits4(ef) : 0u;
    }
    float ed;
    {
        const int q = lane & 31, side = lane >> 5;
        const bool ev = (q < 4) && (side ? !rightE : !leftE);
        ed = ev ? (sigm(edx) - ((edt > 0.5f) ? 1.f : 0.f)) : 0.f;
    }

    // ---- packed neighbor exchange: 8 rows/word -> 4 bpermutes total ----
    uint32_t packA = 0u, packB = 0u;
#pragma unroll
    for (int r = 0; r < 8; ++r)  packA |= mb[r] << (4 * r);
#pragma unroll
    for (int r = 8; r < 10; ++r) packB |= mb[r] << (4 * (r - 8));
    const uint32_t mlA = __shfl_up(packA, 1),  mlB = __shfl_up(packB, 1);
    const uint32_t mrA = __shfl_down(packA, 1), mrB = __shfl_down(packB, 1);

    // ---- morphology: 12-bit window, dilate/erode cascades ----
    uint32_t po[10], pu[10];
#pragma unroll
    for (int r = 0; r < 10; ++r) {
        const uint32_t m = mb[r];
        uint32_t ml = (r < 8 ? (mlA >> (4 * r)) : (mlB >> (4 * (r - 8)))) & 0xFu;
        uint32_t mr = (r < 8 ? (mrA >> (4 * r)) : (mrB >> (4 * (r - 8)))) & 0xFu;
        const uint32_t el = __shfl(eb, r);        // uniform-index readlane (cheap)
        const uint32_t er = __shfl(eb, 32 + r);
        if (lane == 0)  ml = el;
        if (lane == 63) mr = er;
        const uint32_t w = ml | (m << 4) | (mr << 8);    // bit b = col cx-4+b
        const bool rowv = ((unsigned)(y0 - 3 + r) < (unsigned)Hn);
        const uint32_t wc = rowv ? ((~w) & validm) : 0u;
        const uint32_t w1 = w  | (w  << 1) | (w  >> 1);
        const uint32_t w2 = w1 | (w1 << 1) | (w1 >> 1);
        const uint32_t w3 = w2 | (w2 << 1) | (w2 >> 1);
        const uint32_t u1 = wc | (wc << 1) | (wc >> 1);
        const uint32_t u2 = u1 | (u1 << 1) | (u1 >> 1);
        const uint32_t u3 = u2 | (u2 << 1) | (u2 >> 1);
        po[r] = ((w1 >> 4) & 0xFu) | (((w2 >> 4) & 0xFu) << 4) |
                (((w3 >> 4) & 0xFu) << 8);
        pu[r] = ((u1 >> 4) & 0xFu) | (((u2 >> 4) & 0xFu) << 4) |
                (((u3 >> 4) & 0xFu) << 8);
    }

    // ---- d field + bce + elementwise sums ----
    float4 da[6], b4c[4];
    float sbce = 0.f, sd = 0.f, sdt = 0.f, stt = 0.f;
#pragma unroll
    for (int rr = 0; rr < 6; ++rr) {
        const uint32_t m = mb[rr + 2];
        const float t0 = (float)(m & 1u), t1 = (float)((m >> 1) & 1u);
        const float t2 = (float)((m >> 2) & 1u), t3 = (float)((m >> 3) & 1u);
        const float4 x = xf[rr];
        if (rr >= 1 && rr <= 4) {                 // core rows (always valid)
            float4 d, bc;
            pxb(x.x, t0, d.x, bc.x); pxb(x.y, t1, d.y, bc.y);
            pxb(x.z, t2, d.z, bc.z); pxb(x.w, t3, d.w, bc.w);
            da[rr] = d; b4c[rr - 1] = bc;
            sbce += bc.x + bc.y + bc.z + bc.w;
            sd   += d.x + d.y + d.z + d.w;
            sdt  += d.x * t0 + d.y * t1 + d.z * t2 + d.w * t3;
            stt  += t0 + t1 + t2 + t3;
        } else {                                  // halo rows: d only, 0 if OOB
            const bool rowv = ((unsigned)(y0 - 1 + rr) < (unsigned)Hn);
            float4 d;
            pxd(x.x, t0, d.x); pxd(x.y, t1, d.y);
            pxd(x.z, t2, d.z); pxd(x.w, t3, d.w);
            if (!rowv) d = make_float4(0.f, 0.f, 0.f, 0.f);
            da[rr] = d;
        }
    }

    // ---- boundary combine + Laplacian on the 4 core rows ----
    float sb1 = 0.f, sb2 = 0.f, sb3 = 0.f, sdet = 0.f;
    int c1 = 0, c2 = 0, c3 = 0;
#pragma unroll
    for (int k = 0; k < 4; ++k) {                 // core row rr = k+1
        const uint32_t o3 = po[k + 2] | po[k + 3] | po[k + 4];
        const uint32_t o5 = o3 | po[k + 1] | po[k + 5];
        const uint32_t o7 = o5 | po[k] | po[k + 6];
        const uint32_t p3 = pu[k + 2] | pu[k + 3] | pu[k + 4];
        const uint32_t p5 = p3 | pu[k + 1] | pu[k + 5];
        const uint32_t p7 = p5 | pu[k] | pu[k + 6];
        const uint32_t vo = (o3 & 0xFu) | (o5 & 0xF0u) | (o7 & 0xF00u);
        const uint32_t vu = (p3 & 0xFu) | (p5 & 0xF0u) | (p7 & 0xF00u);
        const uint32_t b = vo & vu;               // [0:4) r1, [4:8) r2, [8:12) r3
        c1 += __popc(b & 0xFu);
        c2 += __popc(b & 0xF0u);
        c3 += __popc(b & 0xF00u);
        const float4 bc = b4c[k];
        sb1 += (((b >> 0) & 1) ? bc.x : 0.f) + (((b >> 1) & 1) ? bc.y : 0.f) +
               (((b >> 2) & 1) ? bc.z : 0.f) + (((b >> 3) & 1) ? bc.w : 0.f);
        sb2 += (((b >> 4) & 1) ? bc.x : 0.f) + (((b >> 5) & 1) ? bc.y : 0.f) +
               (((b >> 6) & 1) ? bc.z : 0.f) + (((b >> 7) & 1) ? bc.w : 0.f);
        sb3 += (((b >> 8) & 1) ? bc.x : 0.f) + (((b >> 9) & 1) ? bc.y : 0.f) +
               (((b >> 10) & 1) ? bc.z : 0.f) + (((b >> 11) & 1) ? bc.w : 0.f);

        const float4 ce = da[k + 1];
        const float4 up = da[k];
        const float4 dn = da[k + 2];
        float left = __shfl_up(ce.w, 1);
        { const float el = __shfl(ed, k); if (lane == 0)  left = el; }
        float right = __shfl_down(ce.x, 1);
        { const float er = __shfl(ed, 32 + k); if (lane == 63) right = er; }
        sdet += fabsf(left + ce.y + up.x + dn.x - 4.f * ce.x);
        sdet += fabsf(ce.x + ce.z + up.y + dn.y - 4.f * ce.y);
        sdet += fabsf(ce.y + ce.w + up.z + dn.z - 4.f * ce.z);
        sdet += fabsf(ce.z + right + up.w + dn.w - 4.f * ce.w);
    }

    // ---- block reduction: 3 shuffle levels (8-lane groups) + LDS finish ----
    float acc[NACC];
    acc[0] = sbce; acc[1] = sd; acc[2] = stt; acc[3] = sdt;
    acc[4] = (float)c1; acc[5] = (float)c2; acc[6] = (float)c3;
    acc[7] = sb1; acc[8] = sb2; acc[9] = sb3; acc[10] = sdet;
#pragma unroll
    for (int i = 0; i < NACC; ++i) {
        float v = acc[i];
        v += __shfl_xor(v, 1);
        v += __shfl_xor(v, 2);
        v += __shfl_xor(v, 4);
        acc[i] = v;                               // lanes 0,8,..,56: 8-lane sums
    }
    __shared__ float s_red[32][NACC];             // 4 waves x 8 groups
    if ((lane & 7) == 0) {
#pragma unroll
        for (int i = 0; i < NACC; ++i) s_red[wid * 8 + (lane >> 3)][i] = acc[i];
    }
    __syncthreads();
    if (tid < NACC) {
        float v = 0.f;
#pragma unroll
        for (int g = 0; g < 32; ++g) v += s_red[g][tid];
        partials[(size_t)tid * NBLK + vid] = v;
    }
}

__global__ __launch_bounds__(704) void crack_final(
    const float* __restrict__ partials, float* __restrict__ out)
{
    const int tid = threadIdx.x;                  // 11 waves, one per slot
    const int lane = tid & 63;
    const int w = tid >> 6;                       // 0..10
    __shared__ float s_sum[NACC];

    float v = 0.f;
#pragma unroll
    for (int j = 0; j < NBLK / 64; ++j)           // 16 coalesced loads
        v += partials[(size_t)w * NBLK + j * 64 + lane];
#pragma unroll
    for (int off = 32; off; off >>= 1) v += __shfl_xor(v, off);
    if (lane == 0) s_sum[w] = v;
    __syncthreads();

    if (tid == 0) {
        float t[NACC];
#pragma unroll
        for (int i = 0; i < NACC; ++i) t[i] = s_sum[i];
        const float bce   = t[0] / NTOT;
        const float st    = t[2];
        const float sp    = t[1] + t[2];
        const float inter = t[3] + t[2];
        const float dice = 1.f - (2.f * inter + 1.f) / (sp + st + 1.f);
        const float fp = sp - inter, fn = st - inter;
        const float tvi = (inter + 1.f) / (inter + 0.6f * fp + 0.4f * fn + 1.f);
        const float tversky = powf(fmaxf(1.f - tvi, 0.f), 0.75f);
        float tb = 0.f, ns = 0.f;
        for (int i = 0; i < 3; ++i) {
            const float cnt = t[4 + i], sb = t[7 + i];
            if (cnt >= 1.f) { tb += sb / cnt; ns += 1.f; }
        }
        const float boundary = (ns > 0.f) ? tb / ns : 0.f;
        const float detail = t[10] / NTOT;
        out[0] = bce + dice + 0.5f * tversky + 0.5f * boundary + 0.3f * detail;
    }
}

extern "C" void kernel_launch(void* const* d_in, const int* in_sizes, int n_in,
                              void* d_out, int out_size, void* d_ws, size_t ws_size,
                              hipStream_t stream) {
    const float* logits = (const float*)d_in[0];
    const float* target = (const float*)d_in[1];
    float* partials = (float*)d_ws;   // NACC * NBLK floats = 45 KiB, fully overwritten

    dim3 grid(GX, GY, Bn);
    crack_main<<<grid, dim3(256), 0, stream>>>(logits, target, partials);
    crack_final<<<1, 704, 0, stream>>>(partials, (float*)d_out);
}